// Round 6
// baseline (123.222 us; speedup 1.0000x reference)
//
#include <hip/hip_runtime.h>

#define MAX_FTS 30
#define HALF 256
#define ROWLEN 257

typedef __attribute__((ext_vector_type(2))) _Float16 f16x2;
typedef __attribute__((ext_vector_type(4))) _Float16 f16x4;
typedef __attribute__((ext_vector_type(8))) _Float16 f16x8;
typedef __attribute__((ext_vector_type(4))) float    f32x4;
typedef __attribute__((ext_vector_type(2))) unsigned int u32x2;

// ---------------------------------------------------------------------------
// Pass 0a: per-row int8 quantization of ft_w fts columns (biased uint8,
// per-row f32 scale), one wave per row; also extracts the f32 psqt column.
// ---------------------------------------------------------------------------
__global__ __launch_bounds__(256) void quant_rows(
    const float* __restrict__ ft_w,
    unsigned char* __restrict__ tbl8,
    float* __restrict__ scl, float* __restrict__ psq, int n_fts)
{
    const int wv = threadIdx.x >> 6, l = threadIdx.x & 63;
    const int r = blockIdx.x * 4 + wv;
    if (r >= n_fts) return;
    const float* row = ft_w + (size_t)r * ROWLEN;

    float v[4];
#pragma unroll
    for (int k = 0; k < 4; ++k) v[k] = row[(l << 2) + k];

    float m = fmaxf(fmaxf(fabsf(v[0]), fabsf(v[1])), fmaxf(fabsf(v[2]), fabsf(v[3])));
#pragma unroll
    for (int d = 1; d < 64; d <<= 1) m = fmaxf(m, __shfl_xor(m, d, 64));

    const float s   = m * (1.0f / 127.0f);
    const float inv = (m > 0.0f) ? (127.0f / m) : 0.0f;

    unsigned int u = 0;
#pragma unroll
    for (int k = 0; k < 4; ++k) {
        int q = (int)rintf(v[k] * inv) + 128;
        u |= ((unsigned int)q & 0xffu) << (8 * k);
    }
    *(unsigned int*)(tbl8 + (size_t)r * 256 + (l << 2)) = u;
    if (l == 0) { scl[r] = s; psq[r] = row[HALF]; }
}

// ---------------------------------------------------------------------------
// Pass 0b: fc1_w -> fp16; zero row (biased 0x80) at index n_fts; zero scale/psq.
// ---------------------------------------------------------------------------
__global__ __launch_bounds__(256) void convert_misc(
    const float* __restrict__ fc1_w, _Float16* __restrict__ w1h,
    unsigned char* __restrict__ tbl8, float* __restrict__ scl,
    float* __restrict__ psq, int n_fts)
{
    const int i = blockIdx.x * 256 + threadIdx.x;
    if (i < 32 * 2 * HALF) w1h[i] = (_Float16)fc1_w[i];
    if (blockIdx.x == 0) {
        if (threadIdx.x < 64)
            ((unsigned int*)(tbl8 + (size_t)n_fts * 256))[threadIdx.x] = 0x80808080u;
        if (threadIdx.x == 64) { scl[n_fts] = 0.0f; psq[n_fts] = 0.0f; }
    }
}

// ---------------------------------------------------------------------------
// Main: one sample per WAVE. Paired-perspective gathers: lanes 0-31 fetch
// the w-row, lanes 32-63 the b-row, 8B/lane -> 30 dwordx2 loads, ALL issued
// into a register array before any consumption (max memory-level parallelism).
// Dequant+accumulate afterwards; shfl_xor(32) swaps perspectives for the lerp.
// ---------------------------------------------------------------------------
__global__ __launch_bounds__(256, 4) void nnue_wave(
    const int* __restrict__ wft, const int* __restrict__ bft,
    const float* __restrict__ stm,
    const unsigned char* __restrict__ tbl8, const float* __restrict__ scl,
    const float* __restrict__ psq, const _Float16* __restrict__ w1h,
    const float* __restrict__ ft_b,
    const float* __restrict__ fc1_b, const float* __restrict__ fc2_w,
    const float* __restrict__ fc2_b, const float* __restrict__ fco_w,
    const float* __restrict__ fco_b,
    float* __restrict__ out, int B, int zr)
{
    const int t  = threadIdx.x;
    const int wv = t >> 6;
    const int l  = t & 63;
    const int c  = l & 31;   // element group: elements 8c..8c+7
    const int h  = l >> 5;   // 0: w-perspective, 1: b-perspective
    const int s  = (blockIdx.x << 2) + wv;

    __shared__ __attribute__((aligned(16))) _Float16 s_x[4][512];
    __shared__ float s_h1[4][32];

    if (s >= B) return;

    // ---- prefetch indices + per-row scales + psqt into lane registers ----
    const int lc  = (l < MAX_FTS) ? l : (MAX_FTS - 1);
    const int iwv = wft[s * MAX_FTS + lc];
    const int ibv = bft[s * MAX_FTS + lc];
    const int cwl = (iwv < 0) ? zr : iwv;
    const int cbl = (ibv < 0) ? zr : ibv;

    float swv_ = 0.0f, sbv_ = 0.0f, pv = 0.0f;
    if (l < MAX_FTS) {
        swv_ = scl[cwl];
        sbv_ = scl[cbl];
        pv   = psq[cwl] - psq[cbl];
    }
    const int swv_i = __builtin_bit_cast(int, swv_);
    const int sbv_i = __builtin_bit_cast(int, sbv_);

    // ---- issue ALL 30 paired row gathers (8B/lane, 512B/instr) ----
    u32x2 q[MAX_FTS];
    const unsigned char* gb = tbl8 + (c << 3);
#pragma unroll
    for (int i = 0; i < MAX_FTS; ++i) {
        int icw = __builtin_amdgcn_readlane(iwv, i);
        icw = (icw < 0) ? zr : icw;
        int icb = __builtin_amdgcn_readlane(ibv, i);
        icb = (icb < 0) ? zr : icb;
        const int ic = h ? icb : icw;
        q[i] = *(const u32x2*)(gb + ((size_t)ic << 8));
    }

    // ---- dequant + accumulate (8 elements per lane, own perspective) ----
    float acc[8];
#pragma unroll
    for (int k = 0; k < 8; ++k) acc[k] = 0.0f;
#pragma unroll
    for (int i = 0; i < MAX_FTS; ++i) {
        const float sw = __builtin_bit_cast(float, __builtin_amdgcn_readlane(swv_i, i));
        const float sb = __builtin_bit_cast(float, __builtin_amdgcn_readlane(sbv_i, i));
        const float sc = h ? sb : sw;
        const unsigned int a0 = q[i].x, a1 = q[i].y;
        acc[0] = fmaf(sc, (float)( a0        & 0xffu), acc[0]);
        acc[1] = fmaf(sc, (float)((a0 >>  8) & 0xffu), acc[1]);
        acc[2] = fmaf(sc, (float)((a0 >> 16) & 0xffu), acc[2]);
        acc[3] = fmaf(sc, (float)( a0 >> 24        ), acc[3]);
        acc[4] = fmaf(sc, (float)( a1        & 0xffu), acc[4]);
        acc[5] = fmaf(sc, (float)((a1 >>  8) & 0xffu), acc[5]);
        acc[6] = fmaf(sc, (float)((a1 >> 16) & 0xffu), acc[6]);
        acc[7] = fmaf(sc, (float)( a1 >> 24        ), acc[7]);
    }

    // ---- butterflies: scale sums (bias removal) + psqt diff ----
    float ssw = swv_, ssb = sbv_;
#pragma unroll
    for (int d = 1; d < 64; d <<= 1) {
        ssw += __shfl_xor(ssw, d, 64);
        ssb += __shfl_xor(ssb, d, 64);
        pv  += __shfl_xor(pv,  d, 64);
    }
    const float bias = 128.0f * (h ? ssb : ssw);
#pragma unroll
    for (int k = 0; k < 8; ++k) acc[k] -= bias;

    // ---- exchange perspectives, lerp + ft_b + clip, stage to LDS ----
    const float st = stm[s];
    const float os = 1.0f - st;
    const float* fbp = ft_b + (c << 3);
    f16x8 hx;
#pragma unroll
    for (int k = 0; k < 8; ++k) {
        const float other = __shfl_xor(acc[k], 32, 64);
        const float x = os * acc[k] + st * other + fbp[k];
        hx[k] = (_Float16)fminf(fmaxf(x, 0.0f), 1.0f);
    }
    *(f16x8*)(&s_x[wv][(h << 8) + (c << 3)]) = hx;
    __builtin_amdgcn_wave_barrier();
    asm volatile("" ::: "memory");

    // ---- FC1: lane (j=l&31, hf=l>>5) does 256 MACs via dot2, 4 acc chains ----
    const int j  = c;
    const int hf = h;
    const _Float16* w1p = w1h + (j << 9) + (hf << 8);
    const _Float16* xs  = &s_x[wv][hf << 8];
    float acc0 = 0.0f, acc1 = 0.0f, acc2 = 0.0f, acc3 = 0.0f;
#pragma unroll
    for (int i = 0; i < 32; ++i) {
        const f16x8 wv8 = *(const f16x8*)(w1p + (i << 3));
        const f16x8 xv8 = *(const f16x8*)(xs  + (i << 3));
        f16x2 a0 = {wv8[0], wv8[1]}, b0 = {xv8[0], xv8[1]};
        f16x2 a1 = {wv8[2], wv8[3]}, b1 = {xv8[2], xv8[3]};
        f16x2 a2 = {wv8[4], wv8[5]}, b2 = {xv8[4], xv8[5]};
        f16x2 a3 = {wv8[6], wv8[7]}, b3 = {xv8[6], xv8[7]};
#if __has_builtin(__builtin_amdgcn_fdot2)
        acc0 = __builtin_amdgcn_fdot2(a0, b0, acc0, false);
        acc1 = __builtin_amdgcn_fdot2(a1, b1, acc1, false);
        acc2 = __builtin_amdgcn_fdot2(a2, b2, acc2, false);
        acc3 = __builtin_amdgcn_fdot2(a3, b3, acc3, false);
#else
        acc0 = fmaf((float)a0[0], (float)b0[0], fmaf((float)a0[1], (float)b0[1], acc0));
        acc1 = fmaf((float)a1[0], (float)b1[0], fmaf((float)a1[1], (float)b1[1], acc1));
        acc2 = fmaf((float)a2[0], (float)b2[0], fmaf((float)a2[1], (float)b2[1], acc2));
        acc3 = fmaf((float)a3[0], (float)b3[0], fmaf((float)a3[1], (float)b3[1], acc3));
#endif
    }
    float part = (acc0 + acc1) + (acc2 + acc3);
    part += __shfl_xor(part, 32, 64);
    const float h1 = fminf(fmaxf(part + fc1_b[j], 0.0f), 1.0f);
    if (l < 32) s_h1[wv][j] = h1;
    __builtin_amdgcn_wave_barrier();
    asm volatile("" ::: "memory");

    // ---- FC2 (duplicated across half-waves) ----
    float a2v = fc2_b[j];
    const float* w2 = fc2_w + (j << 5);
#pragma unroll
    for (int k = 0; k < 32; ++k) a2v = fmaf(s_h1[wv][k], w2[k], a2v);
    const float h2 = fminf(fmaxf(a2v, 0.0f), 1.0f);

    // ---- FCO: 32-lane butterfly dot ----
    float o = h2 * fco_w[j];
    o += __shfl_xor(o, 1, 64);
    o += __shfl_xor(o, 2, 64);
    o += __shfl_xor(o, 4, 64);
    o += __shfl_xor(o, 8, 64);
    o += __shfl_xor(o, 16, 64);
    if (l == 0) out[s] = o + fco_b[0] + pv * (0.5f - st);
}

// ---------------------------------------------------------------------------
// Fallback (verified R1 f32 kernel) — used only if ws is too small.
// ---------------------------------------------------------------------------
__global__ __launch_bounds__(256) void nnue_fwd(
    const int* __restrict__ wft, const int* __restrict__ bft,
    const float* __restrict__ stm, const float* __restrict__ ft_w,
    const float* __restrict__ ft_b, const float* __restrict__ fc1_w,
    const float* __restrict__ fc1_b, const float* __restrict__ fc2_w,
    const float* __restrict__ fc2_b, const float* __restrict__ fco_w,
    const float* __restrict__ fco_b, float* __restrict__ out)
{
    const int s = blockIdx.x;
    const int t = threadIdx.x;
    __shared__ int   s_iw[MAX_FTS];
    __shared__ int   s_ib[MAX_FTS];
    __shared__ float s_xx[2 * HALF];
    __shared__ float s_a[32];
    __shared__ float s_b[32];
    __shared__ float s_ps[2];

    if (t < MAX_FTS)                      s_iw[t]      = wft[s * MAX_FTS + t];
    else if (t >= 64 && t < 64 + MAX_FTS) s_ib[t - 64] = bft[s * MAX_FTS + (t - 64)];
    __syncthreads();

    float accw = ft_b[t];
    float accb = ft_b[t];
#pragma unroll
    for (int i = 0; i < MAX_FTS; ++i) {
        int icw = __builtin_amdgcn_readfirstlane(s_iw[i]);
        int icb = __builtin_amdgcn_readfirstlane(s_ib[i]);
        float mw = icw >= 0 ? 1.0f : 0.0f;
        float mb = icb >= 0 ? 1.0f : 0.0f;
        int ow = (icw >= 0 ? icw : 0) * ROWLEN;
        int ob = (icb >= 0 ? icb : 0) * ROWLEN;
        accw = fmaf(ft_w[ow + t], mw, accw);
        accb = fmaf(ft_w[ob + t], mb, accb);
    }
    if (t == 0 || t == 64) {
        const int* idx = (t == 0) ? s_iw : s_ib;
        float ps = 0.0f;
#pragma unroll
        for (int i = 0; i < MAX_FTS; ++i) {
            int ic = idx[i];
            float m = ic >= 0 ? 1.0f : 0.0f;
            int o = (ic >= 0 ? ic : 0) * ROWLEN;
            ps = fmaf(ft_w[o + HALF], m, ps);
        }
        s_ps[t == 0 ? 0 : 1] = ps;
    }
    const float st = stm[s];
    float xl = (1.0f - st) * accw + st * accb;
    float xh = (1.0f - st) * accb + st * accw;
    s_xx[t]        = fminf(fmaxf(xl, 0.0f), 1.0f);
    s_xx[t + HALF] = fminf(fmaxf(xh, 0.0f), 1.0f);
    __syncthreads();

    const int j = t >> 3, p = t & 7;
    const float* w1 = fc1_w + j * (2 * HALF);
    float part = 0.0f;
#pragma unroll
    for (int i = 0; i < 64; ++i) {
        int k = (i << 3) | p;
        part = fmaf(s_xx[k], w1[k], part);
    }
    part += __shfl_xor(part, 1, 64);
    part += __shfl_xor(part, 2, 64);
    part += __shfl_xor(part, 4, 64);
    if (p == 0) s_a[j] = fminf(fmaxf(part + fc1_b[j], 0.0f), 1.0f);
    __syncthreads();

    if (t < 32) {
        float a = fc2_b[t];
        const float* w2 = fc2_w + t * 32;
#pragma unroll
        for (int k = 0; k < 32; ++k) a = fmaf(s_a[k], w2[k], a);
        s_b[t] = fminf(fmaxf(a, 0.0f), 1.0f);
    }
    __syncthreads();

    if (t == 0) {
        float o = fco_b[0];
#pragma unroll
        for (int k = 0; k < 32; ++k) o = fmaf(s_b[k], fco_w[k], o);
        o += (s_ps[0] - s_ps[1]) * (0.5f - st);
        out[s] = o;
    }
}

extern "C" void kernel_launch(void* const* d_in, const int* in_sizes, int n_in,
                              void* d_out, int out_size, void* d_ws, size_t ws_size,
                              hipStream_t stream) {
    const int*   wft   = (const int*)  d_in[0];
    const int*   bft   = (const int*)  d_in[1];
    const float* stm   = (const float*)d_in[2];
    const float* ft_w  = (const float*)d_in[3];
    const float* ft_b  = (const float*)d_in[4];
    const float* fc1_w = (const float*)d_in[5];
    const float* fc1_b = (const float*)d_in[6];
    const float* fc2_w = (const float*)d_in[7];
    const float* fc2_b = (const float*)d_in[8];
    const float* fco_w = (const float*)d_in[9];
    const float* fco_b = (const float*)d_in[10];
    float* out = (float*)d_out;

    const int B     = in_sizes[0] / MAX_FTS;
    const int n_fts = in_sizes[3] / ROWLEN;

    const size_t colpad    = (((size_t)(n_fts + 1) * sizeof(float)) + 15) & ~(size_t)15;
    const size_t w1h_bytes = (size_t)32 * 2 * HALF * sizeof(_Float16);
    const size_t tbl_bytes = (size_t)(n_fts + 1) * 256;
    const size_t need = 2 * colpad + w1h_bytes + tbl_bytes;

    if (ws_size >= need) {
        float*         scl  = (float*)d_ws;
        float*         psq  = (float*)((char*)d_ws + colpad);
        _Float16*      w1h  = (_Float16*)((char*)d_ws + 2 * colpad);
        unsigned char* tbl8 = (unsigned char*)((char*)d_ws + 2 * colpad + w1h_bytes);

        quant_rows<<<(n_fts + 3) / 4, 256, 0, stream>>>(ft_w, tbl8, scl, psq, n_fts);
        convert_misc<<<64, 256, 0, stream>>>(fc1_w, w1h, tbl8, scl, psq, n_fts);
        nnue_wave<<<(B + 3) / 4, 256, 0, stream>>>(wft, bft, stm, tbl8, scl, psq,
                                                   w1h, ft_b, fc1_b, fc2_w, fc2_b,
                                                   fco_w, fco_b, out, B, n_fts);
    } else {
        nnue_fwd<<<B, 256, 0, stream>>>(wft, bft, stm, ft_w, ft_b,
                                        fc1_w, fc1_b, fc2_w, fc2_b,
                                        fco_w, fco_b, out);
    }
}

// Round 7
// 62.018 us; speedup vs baseline: 1.9869x; 1.9869x over previous
//
#include <hip/hip_runtime.h>

#define MAX_FTS 30
#define HALF 256
#define ROWLEN 257

typedef __attribute__((ext_vector_type(4))) _Float16 f16x4;
typedef __attribute__((ext_vector_type(8))) _Float16 f16x8;
typedef __attribute__((ext_vector_type(4))) float    f32x4;

// ---------------------------------------------------------------------------
// Pass 0a: per-row int8 quantization of ft_w (biased uint8 + per-row f32
// scale), one wave per row; extracts f32 psqt column.
// ---------------------------------------------------------------------------
__global__ __launch_bounds__(256) void quant_rows(
    const float* __restrict__ ft_w,
    unsigned char* __restrict__ tbl8,
    float* __restrict__ scl, float* __restrict__ psq, int n_fts)
{
    const int wv = threadIdx.x >> 6, l = threadIdx.x & 63;
    const int r = blockIdx.x * 4 + wv;
    if (r >= n_fts) return;
    const float* row = ft_w + (size_t)r * ROWLEN;

    float v[4];
#pragma unroll
    for (int k = 0; k < 4; ++k) v[k] = row[(l << 2) + k];

    float m = fmaxf(fmaxf(fabsf(v[0]), fabsf(v[1])), fmaxf(fabsf(v[2]), fabsf(v[3])));
#pragma unroll
    for (int d = 1; d < 64; d <<= 1) m = fmaxf(m, __shfl_xor(m, d, 64));

    const float s   = m * (1.0f / 127.0f);
    const float inv = (m > 0.0f) ? (127.0f / m) : 0.0f;

    unsigned int u = 0;
#pragma unroll
    for (int k = 0; k < 4; ++k) {
        int q = (int)rintf(v[k] * inv) + 128;
        u |= ((unsigned int)q & 0xffu) << (8 * k);
    }
    *(unsigned int*)(tbl8 + (size_t)r * 256 + (l << 2)) = u;
    if (l == 0) { scl[r] = s; psq[r] = row[HALF]; }
}

// ---------------------------------------------------------------------------
// Pass 0b: build MFMA B-fragments for fc1 (2 ntiles x 16 ksteps) and fc2
// (2 ntiles); zero row + zero scale/psqt sentinel.
// Fragment layout (16x16x32): lane holds B[k=(lane>>4)*8+e][col=lane&15].
// ---------------------------------------------------------------------------
__global__ __launch_bounds__(256) void build_frags(
    const float* __restrict__ fc1_w, const float* __restrict__ fc2_w,
    _Float16* __restrict__ w1f, _Float16* __restrict__ w2f,
    unsigned char* __restrict__ tbl8, float* __restrict__ scl,
    float* __restrict__ psq, int n_fts)
{
    const int idx = blockIdx.x * 256 + threadIdx.x;
    if (idx < 16384) {
        const int nt = idx >> 13, ks = (idx >> 9) & 15, ln = (idx >> 3) & 63, e = idx & 7;
        w1f[idx] = (_Float16)fc1_w[(nt * 16 + (ln & 15)) * 512 + ks * 32 + (ln >> 4) * 8 + e];
    } else if (idx < 16384 + 1024) {
        const int k = idx - 16384;
        const int n2 = k >> 9, ln = (k >> 3) & 63, e = k & 7;
        w2f[k] = (_Float16)fc2_w[(n2 * 16 + (ln & 15)) * 32 + (ln >> 4) * 8 + e];
    } else if (idx < 16384 + 1024 + 64) {
        ((unsigned int*)(tbl8 + (size_t)n_fts * 256))[idx - 17408] = 0x80808080u;
    } else if (idx == 16384 + 1024 + 64) {
        scl[n_fts] = 0.0f; psq[n_fts] = 0.0f;
    }
}

// ---------------------------------------------------------------------------
// K1: pure gather/FT, one sample per wave (R5 structure). Writes clipped x
// (fp16, 512 halves/sample) and the psqt term; NO fully-connected work.
// ---------------------------------------------------------------------------
__global__ __launch_bounds__(256) void k1_gather(
    const int* __restrict__ wft, const int* __restrict__ bft,
    const float* __restrict__ stm,
    const unsigned char* __restrict__ tbl8, const float* __restrict__ scl,
    const float* __restrict__ psq, const float* __restrict__ ft_b,
    _Float16* __restrict__ X, float* __restrict__ psterm, int B, int zr)
{
    const int t  = threadIdx.x;
    const int wv = t >> 6;
    const int l  = t & 63;
    const int s  = (blockIdx.x << 2) + wv;
    if (s >= B) return;

    const int lc  = (l < MAX_FTS) ? l : (MAX_FTS - 1);
    const int iwv = wft[s * MAX_FTS + lc];
    const int ibv = bft[s * MAX_FTS + lc];
    const int cwl = (iwv < 0) ? zr : iwv;
    const int cbl = (ibv < 0) ? zr : ibv;

    float swv_ = 0.0f, sbv_ = 0.0f, pv = 0.0f;
    if (l < MAX_FTS) {
        swv_ = scl[cwl];
        sbv_ = scl[cbl];
        pv   = psq[cwl] - psq[cbl];
    }
    const int swi = __builtin_bit_cast(int, swv_);
    const int sbi = __builtin_bit_cast(int, sbv_);

    f32x4 aw = {0.0f, 0.0f, 0.0f, 0.0f};
    f32x4 ab = {0.0f, 0.0f, 0.0f, 0.0f};
    const unsigned char* gb = tbl8 + (l << 2);
#pragma unroll
    for (int i = 0; i < MAX_FTS; ++i) {
        int icw = __builtin_amdgcn_readlane(iwv, i);
        icw = (icw < 0) ? zr : icw;
        const unsigned int qw = *(const unsigned int*)(gb + ((size_t)icw << 8));
        const float sw = __builtin_bit_cast(float, __builtin_amdgcn_readlane(swi, i));
        aw[0] = fmaf(sw, (float)( qw        & 0xffu), aw[0]);
        aw[1] = fmaf(sw, (float)((qw >>  8) & 0xffu), aw[1]);
        aw[2] = fmaf(sw, (float)((qw >> 16) & 0xffu), aw[2]);
        aw[3] = fmaf(sw, (float)( qw >> 24        ), aw[3]);

        int icb = __builtin_amdgcn_readlane(ibv, i);
        icb = (icb < 0) ? zr : icb;
        const unsigned int qb = *(const unsigned int*)(gb + ((size_t)icb << 8));
        const float sb = __builtin_bit_cast(float, __builtin_amdgcn_readlane(sbi, i));
        ab[0] = fmaf(sb, (float)( qb        & 0xffu), ab[0]);
        ab[1] = fmaf(sb, (float)((qb >>  8) & 0xffu), ab[1]);
        ab[2] = fmaf(sb, (float)((qb >> 16) & 0xffu), ab[2]);
        ab[3] = fmaf(sb, (float)( qb >> 24        ), ab[3]);
    }

    float ssw = swv_, ssb = sbv_;
#pragma unroll
    for (int d = 1; d < 64; d <<= 1) {
        ssw += __shfl_xor(ssw, d, 64);
        ssb += __shfl_xor(ssb, d, 64);
        pv  += __shfl_xor(pv,  d, 64);
    }

    const f32x4 fb = *(const f32x4*)(ft_b + (l << 2));
    const float st = stm[s];
    const float os = 1.0f - st;
    const float bw = 128.0f * ssw;
    const float bb = 128.0f * ssb;
    f16x4 hxl, hxh;
#pragma unroll
    for (int k = 0; k < 4; ++k) {
        const float accw = (aw[k] - bw) + fb[k];
        const float accb = (ab[k] - bb) + fb[k];
        float xl = os * accw + st * accb;
        float xh = os * accb + st * accw;
        hxl[k] = (_Float16)fminf(fmaxf(xl, 0.0f), 1.0f);
        hxh[k] = (_Float16)fminf(fmaxf(xh, 0.0f), 1.0f);
    }
    _Float16* xp = X + (size_t)s * 512;
    *(f16x4*)(xp + (l << 2))        = hxl;
    *(f16x4*)(xp + HALF + (l << 2)) = hxh;
    if (l == 0) psterm[s] = pv * (0.5f - st);
}

// ---------------------------------------------------------------------------
// K2: batched MLP via MFMA. One wave = 16 samples. FC1: 32 mfma (2 ntiles x
// 16 ksteps); FC2: 2 mfma; FCO: shuffle-reduced dot. D layout (m89):
// col=lane&15, row=(lane>>4)*4+reg.
// ---------------------------------------------------------------------------
__global__ __launch_bounds__(256) void k2_mlp(
    const _Float16* __restrict__ X,
    const _Float16* __restrict__ w1f, const _Float16* __restrict__ w2f,
    const float* __restrict__ fc1_b, const float* __restrict__ fc2_b,
    const float* __restrict__ fco_w, const float* __restrict__ fco_b,
    const float* __restrict__ psterm, float* __restrict__ out, int B)
{
    const int t   = threadIdx.x;
    const int wv  = t >> 6;
    const int l   = t & 63;
    const int col = l & 15;
    const int qk  = l >> 4;
    const int s0  = blockIdx.x * 64 + wv * 16;
    if (s0 >= B) return;

    __shared__ __attribute__((aligned(16))) _Float16 h1l[4][16][40];

    f32x4 acc0 = {0.0f, 0.0f, 0.0f, 0.0f};
    f32x4 acc1 = {0.0f, 0.0f, 0.0f, 0.0f};
    const _Float16* xp = X + (size_t)(s0 + col) * 512 + qk * 8;
#pragma unroll
    for (int ks = 0; ks < 16; ++ks) {
        const f16x8 a  = *(const f16x8*)(xp + ks * 32);
        const f16x8 b0 = *(const f16x8*)(w1f + ((size_t)(ks)      * 64 + l) * 8);
        const f16x8 b1 = *(const f16x8*)(w1f + ((size_t)(16 + ks) * 64 + l) * 8);
        acc0 = __builtin_amdgcn_mfma_f32_16x16x32_f16(a, b0, acc0, 0, 0, 0);
        acc1 = __builtin_amdgcn_mfma_f32_16x16x32_f16(a, b1, acc1, 0, 0, 0);
    }

    const float b1a = fc1_b[col], b1b = fc1_b[16 + col];
#pragma unroll
    for (int r = 0; r < 4; ++r) {
        h1l[wv][qk * 4 + r][col]      = (_Float16)fminf(fmaxf(acc0[r] + b1a, 0.0f), 1.0f);
        h1l[wv][qk * 4 + r][16 + col] = (_Float16)fminf(fmaxf(acc1[r] + b1b, 0.0f), 1.0f);
    }
    __builtin_amdgcn_wave_barrier();
    asm volatile("" ::: "memory");

    // A2 frag: lane holds h1[row=col][k=qk*8..qk*8+7]
    const f16x8 a2  = *(const f16x8*)(&h1l[wv][col][qk * 8]);
    const f16x8 b20 = *(const f16x8*)(w2f + (size_t)l * 8);
    const f16x8 b21 = *(const f16x8*)(w2f + 512 + (size_t)l * 8);
    f32x4 d0 = {0.0f, 0.0f, 0.0f, 0.0f};
    f32x4 d1 = {0.0f, 0.0f, 0.0f, 0.0f};
    d0 = __builtin_amdgcn_mfma_f32_16x16x32_f16(a2, b20, d0, 0, 0, 0);
    d1 = __builtin_amdgcn_mfma_f32_16x16x32_f16(a2, b21, d1, 0, 0, 0);

    const float b2a = fc2_b[col],  b2b = fc2_b[16 + col];
    const float fwa = fco_w[col],  fwb = fco_w[16 + col];
    float p[4];
#pragma unroll
    for (int r = 0; r < 4; ++r) {
        const float h2a = fminf(fmaxf(d0[r] + b2a, 0.0f), 1.0f);
        const float h2b = fminf(fmaxf(d1[r] + b2b, 0.0f), 1.0f);
        p[r] = h2a * fwa + h2b * fwb;
    }
#pragma unroll
    for (int r = 0; r < 4; ++r) {
        p[r] += __shfl_xor(p[r], 1, 64);
        p[r] += __shfl_xor(p[r], 2, 64);
        p[r] += __shfl_xor(p[r], 4, 64);
        p[r] += __shfl_xor(p[r], 8, 64);
    }
    if (col == 0) {
        const float ob = fco_b[0];
#pragma unroll
        for (int r = 0; r < 4; ++r) {
            const int s = s0 + qk * 4 + r;
            out[s] = p[r] + ob + psterm[s];
        }
    }
}

// ---------------------------------------------------------------------------
// Fallback (verified R1 f32 kernel) — used only if ws is too small.
// ---------------------------------------------------------------------------
__global__ __launch_bounds__(256) void nnue_fwd(
    const int* __restrict__ wft, const int* __restrict__ bft,
    const float* __restrict__ stm, const float* __restrict__ ft_w,
    const float* __restrict__ ft_b, const float* __restrict__ fc1_w,
    const float* __restrict__ fc1_b, const float* __restrict__ fc2_w,
    const float* __restrict__ fc2_b, const float* __restrict__ fco_w,
    const float* __restrict__ fco_b, float* __restrict__ out)
{
    const int s = blockIdx.x;
    const int t = threadIdx.x;
    __shared__ int   s_iw[MAX_FTS];
    __shared__ int   s_ib[MAX_FTS];
    __shared__ float s_xx[2 * HALF];
    __shared__ float s_a[32];
    __shared__ float s_b[32];
    __shared__ float s_ps[2];

    if (t < MAX_FTS)                      s_iw[t]      = wft[s * MAX_FTS + t];
    else if (t >= 64 && t < 64 + MAX_FTS) s_ib[t - 64] = bft[s * MAX_FTS + (t - 64)];
    __syncthreads();

    float accw = ft_b[t];
    float accb = ft_b[t];
#pragma unroll
    for (int i = 0; i < MAX_FTS; ++i) {
        int icw = __builtin_amdgcn_readfirstlane(s_iw[i]);
        int icb = __builtin_amdgcn_readfirstlane(s_ib[i]);
        float mw = icw >= 0 ? 1.0f : 0.0f;
        float mb = icb >= 0 ? 1.0f : 0.0f;
        int ow = (icw >= 0 ? icw : 0) * ROWLEN;
        int ob = (icb >= 0 ? icb : 0) * ROWLEN;
        accw = fmaf(ft_w[ow + t], mw, accw);
        accb = fmaf(ft_w[ob + t], mb, accb);
    }
    if (t == 0 || t == 64) {
        const int* idx = (t == 0) ? s_iw : s_ib;
        float ps = 0.0f;
#pragma unroll
        for (int i = 0; i < MAX_FTS; ++i) {
            int ic = idx[i];
            float m = ic >= 0 ? 1.0f : 0.0f;
            int o = (ic >= 0 ? ic : 0) * ROWLEN;
            ps = fmaf(ft_w[o + HALF], m, ps);
        }
        s_ps[t == 0 ? 0 : 1] = ps;
    }
    const float st = stm[s];
    float xl = (1.0f - st) * accw + st * accb;
    float xh = (1.0f - st) * accb + st * accw;
    s_xx[t]        = fminf(fmaxf(xl, 0.0f), 1.0f);
    s_xx[t + HALF] = fminf(fmaxf(xh, 0.0f), 1.0f);
    __syncthreads();

    const int j = t >> 3, p = t & 7;
    const float* w1 = fc1_w + j * (2 * HALF);
    float part = 0.0f;
#pragma unroll
    for (int i = 0; i < 64; ++i) {
        int k = (i << 3) | p;
        part = fmaf(s_xx[k], w1[k], part);
    }
    part += __shfl_xor(part, 1, 64);
    part += __shfl_xor(part, 2, 64);
    part += __shfl_xor(part, 4, 64);
    if (p == 0) s_a[j] = fminf(fmaxf(part + fc1_b[j], 0.0f), 1.0f);
    __syncthreads();

    if (t < 32) {
        float a = fc2_b[t];
        const float* w2 = fc2_w + t * 32;
#pragma unroll
        for (int k = 0; k < 32; ++k) a = fmaf(s_a[k], w2[k], a);
        s_b[t] = fminf(fmaxf(a, 0.0f), 1.0f);
    }
    __syncthreads();

    if (t == 0) {
        float o = fco_b[0];
#pragma unroll
        for (int k = 0; k < 32; ++k) o = fmaf(s_b[k], fco_w[k], o);
        o += (s_ps[0] - s_ps[1]) * (0.5f - st);
        out[s] = o;
    }
}

extern "C" void kernel_launch(void* const* d_in, const int* in_sizes, int n_in,
                              void* d_out, int out_size, void* d_ws, size_t ws_size,
                              hipStream_t stream) {
    const int*   wft   = (const int*)  d_in[0];
    const int*   bft   = (const int*)  d_in[1];
    const float* stm   = (const float*)d_in[2];
    const float* ft_w  = (const float*)d_in[3];
    const float* ft_b  = (const float*)d_in[4];
    const float* fc1_w = (const float*)d_in[5];
    const float* fc1_b = (const float*)d_in[6];
    const float* fc2_w = (const float*)d_in[7];
    const float* fc2_b = (const float*)d_in[8];
    const float* fco_w = (const float*)d_in[9];
    const float* fco_b = (const float*)d_in[10];
    float* out = (float*)d_out;

    const int B     = in_sizes[0] / MAX_FTS;
    const int n_fts = in_sizes[3] / ROWLEN;

    const size_t colpad = (((size_t)(n_fts + 1) * sizeof(float)) + 15) & ~(size_t)15;
    const size_t w1f_b  = 16384 * sizeof(_Float16);           // 32 KB
    const size_t w2f_b  = 1024 * sizeof(_Float16);            // 2 KB
    const size_t pst_b  = ((size_t)B * sizeof(float) + 15) & ~(size_t)15;
    const size_t x_b    = (size_t)B * 512 * sizeof(_Float16); // 16 MB
    const size_t tbl_b  = (size_t)(n_fts + 1) * 256;
    const size_t need   = 2 * colpad + w1f_b + w2f_b + pst_b + x_b + tbl_b;

    if (ws_size >= need && (B & 63) == 0) {
        char* p = (char*)d_ws;
        float*         scl  = (float*)p;                 p += colpad;
        float*         psq  = (float*)p;                 p += colpad;
        _Float16*      w1f  = (_Float16*)p;              p += w1f_b;
        _Float16*      w2f  = (_Float16*)p;              p += w2f_b;
        float*         pst  = (float*)p;                 p += pst_b;
        _Float16*      X    = (_Float16*)p;              p += x_b;
        unsigned char* tbl8 = (unsigned char*)p;

        quant_rows<<<(n_fts + 3) / 4, 256, 0, stream>>>(ft_w, tbl8, scl, psq, n_fts);
        build_frags<<<69, 256, 0, stream>>>(fc1_w, fc2_w, w1f, w2f, tbl8, scl, psq, n_fts);
        k1_gather<<<(B + 3) / 4, 256, 0, stream>>>(wft, bft, stm, tbl8, scl, psq,
                                                   ft_b, X, pst, B, n_fts);
        k2_mlp<<<B / 64, 256, 0, stream>>>(X, w1f, w2f, fc1_b, fc2_b,
                                           fco_w, fco_b, pst, out, B);
    } else {
        nnue_fwd<<<B, 256, 0, stream>>>(wft, bft, stm, ft_w, ft_b,
                                        fc1_w, fc1_b, fc2_w, fc2_b,
                                        fco_w, fco_b, out);
    }
}